// Round 15
// baseline (53.063 us; speedup 1.0000x reference)
//
#include <hip/hip_runtime.h>
#include <math.h>

#define NATOMS 2000
#define NNBR   30
#define NCONF  8
#define APC    250
#define NRAD   12
#define M3     20
#define H1N    64
#define H2N    32

#define MU(m) (-1.0f + (float)(m) * (2.0f / 19.0f))

typedef __attribute__((ext_vector_type(8))) short short8_t;   // bf16x8 MFMA frag
typedef __attribute__((ext_vector_type(4))) float f32x4;

__device__ __forceinline__ float sigmoidf(float v) {
    return 1.0f / (1.0f + __expf(-v));
}
__device__ __forceinline__ ushort f2bf(float f) {
    unsigned u = __float_as_uint(f);
    u += 0x7FFF + ((u >> 16) & 1);          // RNE
    return (ushort)(u >> 16);
}
__device__ __forceinline__ float bf2f(ushort s) {
    return __uint_as_float(((unsigned)s) << 16);
}

// One atom per 256-thread block. Single-kernel: energies + forces scattered
// directly into d_out (signs folded), no finalize pass.
// MLP fwd+bwd = 4 per-block bf16 MFMA GEMMs (16x16x32).
// Geometry in SoA bank-planes. 3-body bwd: two-pass split-T, bf16x2-packed T.
extern "C" __global__ void __launch_bounds__(256)
fit_main(const float* __restrict__ x, const float* __restrict__ tx,
         const int* __restrict__ uj,
         const float* __restrict__ W1, const float* __restrict__ b1,
         const float* __restrict__ W2, const float* __restrict__ b2,
         const float* __restrict__ W3, const float* __restrict__ b3,
         float* __restrict__ out)
{
    const int tid  = threadIdx.x;
    const int lane = tid & 63;
    const int wid  = tid >> 6;
    const int atom = blockIdx.x;
    const int lr   = lane & 15;     // MFMA row/col index
    const int lg   = lane >> 4;     // MFMA k-group / reg-group
    float* __restrict__ fout = out + NCONF;   // forces [NATOMS][3]

    // SoA geometry planes: index p hits bank p%32 -> conflict-free q reads
    __shared__ float s_ux[32], s_uy[32], s_uz[32], s_fcp[32];
    __shared__ float s_r[32], s_rinv[32], s_sa[32], s_ca[32];
    __shared__ int   s_j[NNBR];
    __shared__ __align__(16) ushort s_descb[32 * 40];  // bf16 desc [p][d]
    __shared__ __align__(16) ushort s_W1b [32 * 72];   // bf16 W1  [d][h]
    __shared__ __align__(16) ushort s_W2tb[32 * 72];   // bf16 W2t [k][h]
    __shared__ __align__(16) ushort s_h1b [32 * 72];   // h1, later g_z1
    __shared__ __align__(16) ushort s_gz2b[32 * 40];   // gz2
    __shared__ __align__(16) float  s_gd  [32 * 44];   // fp32 gd [p][d]
    __shared__ float    s_outp[64];                    // z3 partials
    __shared__ float    s_red[32 * 5];                 // gu0..2, gfc
    __shared__ unsigned s_Tpk[NNBR * 31];              // bf16(T1)<<16 | bf16(T2)

    const float k1  = 0.6283185307179586f;   // pi/5
    const float sq  = 0.6324555320336759f;   // sqrt(2/5)
    const float eta = 45.125f;               // 1/(2*dmu^2)
    const float RHO = 0.36787944117144233f;  // exp(-1)
    const float C2  = -90.25f;               // -2*eta

    // ---------------- A: stage bf16 weights + pair geometry ----------------
#pragma unroll
    for (int i = 0; i < 8; i++) {
        int idx = tid + 256 * i;               // W1 [32][64]
        s_W1b[(idx >> 6) * 72 + (idx & 63)] = f2bf(W1[idx]);
    }
#pragma unroll
    for (int i = 0; i < 8; i++) {
        int idx = tid + 256 * i;               // W2 [64][32] -> [k][h]
        s_W2tb[(idx & 31) * 72 + (idx >> 5)] = f2bf(W2[idx]);
    }
    if (tid < NNBR) {
        int p = atom * NNBR + tid;
        int j = uj[p];
        float d0 = x[atom * 3 + 0] - x[j * 3 + 0] - tx[p * 3 + 0];
        float d1 = x[atom * 3 + 1] - x[j * 3 + 1] - tx[p * 3 + 1];
        float d2 = x[atom * 3 + 2] - x[j * 3 + 2] - tx[p * 3 + 2];
        float r = sqrtf(d0 * d0 + d1 * d1 + d2 * d2);
        float rinv = 1.0f / r;
        float sa, ca;
        __sincosf(k1 * r, &sa, &ca);
        float fc = 0.5f * (ca + 1.0f);
        s_ux[tid] = d0 * rinv; s_uy[tid] = d1 * rinv; s_uz[tid] = d2 * rinv;
        s_fcp[tid] = fc; s_r[tid] = r; s_rinv[tid] = rinv;
        s_sa[tid] = sa; s_ca[tid] = ca;
        s_j[tid] = j;
    } else if (tid < 32) {
        s_ux[tid] = 0.f; s_uy[tid] = 0.f; s_uz[tid] = 0.f; s_fcp[tid] = 0.f;
        s_r[tid] = 1.f; s_rinv[tid] = 1.f; s_sa[tid] = 0.f; s_ca[tid] = 1.f;
    }
    __syncthreads();

    // ------- B+C: rbf (bf16), pad rows, 3-body forward -> s_descb -------
#pragma unroll 1
    for (int t = tid; t < NNBR * NRAD; t += 256) {
        int p = t / NRAD, n = t - p * NRAD;
        float s = __sinf((float)(n + 1) * k1 * s_r[p]);
        s_descb[p * 40 + n] = f2bf(s_fcp[p] * sq * s * s_rinv[p]);
    }
    if (tid < 80) s_descb[30 * 40 + tid] = 0;      // zero pad rows 30,31
    if (tid < 240) {
        int p = tid >> 3, c = tid & 7;
        int q0 = (c < 6) ? 4 * c : 24 + 3 * (c - 6);
        int qn = (c < 6) ? 4 : 3;
        float up0 = s_ux[p], up1 = s_uy[p], up2 = s_uz[p];
        float d3part[M3];
#pragma unroll
        for (int m = 0; m < M3; m++) d3part[m] = 0.f;
        for (int qq = 0; qq < qn; qq++) {
            int q = q0 + qq;
            float fq = (q == p) ? 0.f : s_fcp[q];
            float cs = up0 * s_ux[q] + up1 * s_uy[q] + up2 * s_uz[q];
            float E  = __expf(9.5f * cs);
            float Ei = __expf(-9.5f * cs);
            float t9 = cs - MU(9);
            float h9 = __expf(-eta * t9 * t9);
            float h = h9 * E, rr = E * RHO;
            d3part[10] = fmaf(fq, h, d3part[10]);
#pragma unroll
            for (int m = 11; m < 20; m++) {
                h *= rr; rr *= RHO;
                d3part[m] = fmaf(fq, h, d3part[m]);
            }
            h = h9; rr = RHO * Ei;
            d3part[9] = fmaf(fq, h, d3part[9]);
#pragma unroll
            for (int m = 8; m >= 0; m--) {
                h *= rr; rr *= RHO;
                d3part[m] = fmaf(fq, h, d3part[m]);
            }
        }
#pragma unroll
        for (int m = 0; m < M3; m++) {
            float v = d3part[m];
            v += __shfl_xor(v, 1);
            v += __shfl_xor(v, 2);
            v += __shfl_xor(v, 4);
            if (c == 0) s_descb[p * 40 + NRAD + m] = f2bf(v);
        }
    }
    __syncthreads();

    // ---- GEMM1: z1 = desc @ W1; h1 = sigmoid(z1+b1) -> s_h1b ----
    {
        const int mt = wid & 1, ntb = (wid >> 1) * 2;
        short8_t a = *(const short8_t*)&s_descb[(16 * mt + lr) * 40 + lg * 8];
#pragma unroll
        for (int t = 0; t < 2; t++) {
            int col = 16 * (ntb + t) + lr;
            short8_t b;
#pragma unroll
            for (int j = 0; j < 8; j++)
                b[j] = (short)s_W1b[(lg * 8 + j) * 72 + col];
            f32x4 c = {0.f, 0.f, 0.f, 0.f};
            c = __builtin_amdgcn_mfma_f32_16x16x32_bf16(a, b, c, 0, 0, 0);
            float b1v = b1[col];
#pragma unroll
            for (int rg = 0; rg < 4; rg++) {
                int p = 16 * mt + lg * 4 + rg;
                s_h1b[p * 72 + col] = f2bf(sigmoidf(c[rg] + b1v));
            }
        }
    }
    __syncthreads();

    // ---- GEMM2: z2 = h1 @ W2; gz2 -> s_gz2b; z3 partials ----
    {
        const int mt = wid & 1, nt = wid >> 1;
        f32x4 c = {0.f, 0.f, 0.f, 0.f};
#pragma unroll
        for (int kt = 0; kt < 2; kt++) {
            short8_t a = *(const short8_t*)&s_h1b[(16 * mt + lr) * 72 + kt * 32 + lg * 8];
            short8_t b = *(const short8_t*)&s_W2tb[(16 * nt + lr) * 72 + kt * 32 + lg * 8];
            c = __builtin_amdgcn_mfma_f32_16x16x32_bf16(a, b, c, 0, 0, 0);
        }
        int k2 = 16 * nt + lr;
        float b2v = b2[k2], w3v = W3[k2];
        float op[4];
#pragma unroll
        for (int rg = 0; rg < 4; rg++) {
            int p = 16 * mt + lg * 4 + rg;
            float s = sigmoidf(c[rg] + b2v);
            op[rg] = s * w3v;
            float g = s_fcp[p] * w3v * s * (1.f - s);   // rows>=30: fc plane = 0
            s_gz2b[p * 40 + k2] = f2bf(g);
        }
#pragma unroll
        for (int rg = 0; rg < 4; rg++) {
            op[rg] += __shfl_xor(op[rg], 1);
            op[rg] += __shfl_xor(op[rg], 2);
            op[rg] += __shfl_xor(op[rg], 4);
            op[rg] += __shfl_xor(op[rg], 8);
        }
        if (lr == 0) {
#pragma unroll
            for (int rg = 0; rg < 4; rg++)
                s_outp[nt * 32 + 16 * mt + lg * 4 + rg] = op[rg];
        }
    }
    __syncthreads();

    // ---- GEMM3: gh1 = gz2 @ W2^T; gz1 = gh1*h1*(1-h1) in place ----
    {
        const int mt = wid & 1, ntb = (wid >> 1) * 2;
        short8_t a = *(const short8_t*)&s_gz2b[(16 * mt + lr) * 40 + lg * 8];
#pragma unroll
        for (int t = 0; t < 2; t++) {
            int hcol = 16 * (ntb + t) + lr;
            short8_t b;
#pragma unroll
            for (int j = 0; j < 8; j++)
                b[j] = (short)s_W2tb[(lg * 8 + j) * 72 + hcol];
            f32x4 c = {0.f, 0.f, 0.f, 0.f};
            c = __builtin_amdgcn_mfma_f32_16x16x32_bf16(a, b, c, 0, 0, 0);
#pragma unroll
            for (int rg = 0; rg < 4; rg++) {
                int p = 16 * mt + lg * 4 + rg;
                float hv = bf2f(s_h1b[p * 72 + hcol]);
                s_h1b[p * 72 + hcol] = f2bf(c[rg] * hv * (1.f - hv));
            }
        }
    }
    __syncthreads();

    // ---- GEMM4: gd = gz1 @ W1^T -> s_gd fp32 ----
    {
        const int mt = wid & 1, nt = wid >> 1;
        f32x4 c = {0.f, 0.f, 0.f, 0.f};
#pragma unroll
        for (int kt = 0; kt < 2; kt++) {
            short8_t a = *(const short8_t*)&s_h1b[(16 * mt + lr) * 72 + kt * 32 + lg * 8];
            short8_t b = *(const short8_t*)&s_W1b[(16 * nt + lr) * 72 + kt * 32 + lg * 8];
            c = __builtin_amdgcn_mfma_f32_16x16x32_bf16(a, b, c, 0, 0, 0);
        }
        int d = 16 * nt + lr;
#pragma unroll
        for (int rg = 0; rg < 4; rg++)
            s_gd[(16 * mt + lg * 4 + rg) * 44 + d] = c[rg];
    }
    __syncthreads();

    // ---- I-a: Ap-side sums per ordered (p,q) -> packed T (no Aq loads) ----
    if (tid < 240) {
        int p = tid >> 3, c = tid & 7;
        int q0 = (c < 6) ? 4 * c : 24 + 3 * (c - 6);
        int qn = (c < 6) ? 4 : 3;
        float up0 = s_ux[p], up1 = s_uy[p], up2 = s_uz[p];
        float Ap[M3];
        {
            const f32x4* ap4 = (const f32x4*)(s_gd + p * 44 + NRAD);
#pragma unroll
            for (int t4 = 0; t4 < 5; t4++) {
                f32x4 v = ap4[t4];
                Ap[4 * t4 + 0] = v[0]; Ap[4 * t4 + 1] = v[1];
                Ap[4 * t4 + 2] = v[2]; Ap[4 * t4 + 3] = v[3];
            }
        }
        for (int qq = 0; qq < qn; qq++) {
            int q = q0 + qq;
            float cs = up0 * s_ux[q] + up1 * s_uy[q] + up2 * s_uz[q];
            float E  = __expf(9.5f * cs);
            float Ei = __expf(-9.5f * cs);
            float t9 = cs - MU(9);
            float h9 = __expf(-eta * t9 * t9);
            float SAh = 0.f, SAm = 0.f;
            {
                float h = h9 * E, rr = E * RHO;
#pragma unroll
                for (int m = 10; m < 20; m++) {
                    if (m > 10) { h *= rr; rr *= RHO; }
                    SAh = fmaf(Ap[m], h, SAh);
                    SAm = fmaf(Ap[m], MU(m) * h, SAm);
                }
            }
            {
                float h = h9, rr = RHO * Ei;
#pragma unroll
                for (int m = 9; m >= 0; m--) {
                    if (m < 9) { h *= rr; rr *= RHO; }
                    SAh = fmaf(Ap[m], h, SAh);
                    SAm = fmaf(Ap[m], MU(m) * h, SAm);
                }
            }
            float t1 = cs * SAh - SAm, t2 = SAh;
            unsigned pk = (q == p) ? 0u
                        : (((unsigned)f2bf(t1) << 16) | (unsigned)f2bf(t2));
            s_Tpk[p * 31 + q] = pk;
        }
    }
    __syncthreads();

    // ---- I-b: combine T[p][q] with T[q][p]; shfl-reduced over chunks ----
    if (tid < 240) {
        int p = tid >> 3, c = tid & 7;
        int q0 = (c < 6) ? 4 * c : 24 + 3 * (c - 6);
        int qn = (c < 6) ? 4 : 3;
        float fp_ = s_fcp[p];
        float gu0 = 0.f, gu1 = 0.f, gu2 = 0.f, gfc = 0.f;
        for (int qq = 0; qq < qn; qq++) {
            int q = q0 + qq;
            float fq = s_fcp[q];
            unsigned pkA = s_Tpk[p * 31 + q];
            unsigned pkB = s_Tpk[q * 31 + p];
            float gcos = C2 * (fq * bf2f((ushort)(pkA >> 16))
                             + fp_ * bf2f((ushort)(pkB >> 16)));
            gu0 = fmaf(gcos, s_ux[q], gu0);
            gu1 = fmaf(gcos, s_uy[q], gu1);
            gu2 = fmaf(gcos, s_uz[q], gu2);
            gfc += bf2f((ushort)(pkB & 0xffff));
        }
        gu0 += __shfl_xor(gu0, 1); gu0 += __shfl_xor(gu0, 2); gu0 += __shfl_xor(gu0, 4);
        gu1 += __shfl_xor(gu1, 1); gu1 += __shfl_xor(gu1, 2); gu1 += __shfl_xor(gu1, 4);
        gu2 += __shfl_xor(gu2, 1); gu2 += __shfl_xor(gu2, 2); gu2 += __shfl_xor(gu2, 4);
        gfc += __shfl_xor(gfc, 1); gfc += __shfl_xor(gfc, 2); gfc += __shfl_xor(gfc, 4);
        if (c == 0) {
            s_red[p * 5 + 0] = gu0;
            s_red[p * 5 + 1] = gu1;
            s_red[p * 5 + 2] = gu2;
            s_red[p * 5 + 3] = gfc;
        }
    }
    __syncthreads();

    // ---- K: rbf backward + final per-pair + DIRECT d_out scatter ----
    // forces = -dE/dx: pair-j gets +gd, central atom gets -sum(gd).
    float gd0 = 0.f, gd1 = 0.f, gd2 = 0.f, eij = 0.f;
    if (tid < NNBR) {
        float fc = s_fcp[tid], rinv = s_rinv[tid];
        float sa = s_sa[tid], ca = s_ca[tid];
        float o = b3[0] + s_outp[tid] + s_outp[32 + tid];
        float u0 = s_ux[tid], u1 = s_uy[tid], u2 = s_uz[tid];
        int j = s_j[tid];
        float grp = 0.f, gfp = 0.f;
        float sprev = 0.f, scur = sa, cprev = 1.f, ccur = ca;
#pragma unroll
        for (int d = 0; d < NRAD; d++) {
            float gdv = s_gd[tid * 44 + d];
            float n = (float)(d + 1);
            grp += gdv * fc * sq * rinv * (n * k1 * ccur - scur * rinv);
            gfp += gdv * sq * scur * rinv;
            float snext = 2.f * ca * scur - sprev; sprev = scur; scur = snext;
            float cnext = 2.f * ca * ccur - cprev; cprev = ccur; ccur = cnext;
        }
        float gfc = gfp + s_red[tid * 5 + 3] + o;
        float gu0 = s_red[tid * 5 + 0];
        float gu1 = s_red[tid * 5 + 1];
        float gu2 = s_red[tid * 5 + 2];
        float grf = grp + gfc * (-0.5f * k1 * sa);
        float gdot = gu0 * u0 + gu1 * u1 + gu2 * u2;
        gd0 = grf * u0 + (gu0 - gdot * u0) * rinv;
        gd1 = grf * u1 + (gu1 - gdot * u1) * rinv;
        gd2 = grf * u2 + (gu2 - gdot * u2) * rinv;
        atomicAdd(&fout[j * 3 + 0], gd0);
        atomicAdd(&fout[j * 3 + 1], gd1);
        atomicAdd(&fout[j * 3 + 2], gd2);
        eij = o * fc;
    }
    if (wid == 0) {
#pragma unroll
        for (int off = 32; off > 0; off >>= 1) {
            gd0 += __shfl_xor(gd0, off);
            gd1 += __shfl_xor(gd1, off);
            gd2 += __shfl_xor(gd2, off);
            eij += __shfl_xor(eij, off);
        }
        if (tid == 0) {
            atomicAdd(&fout[atom * 3 + 0], -gd0);
            atomicAdd(&fout[atom * 3 + 1], -gd1);
            atomicAdd(&fout[atom * 3 + 2], -gd2);
            atomicAdd(&out[atom / APC], eij);
        }
    }
}

extern "C" void kernel_launch(void* const* d_in, const int* in_sizes, int n_in,
                              void* d_out, int out_size, void* d_ws, size_t ws_size,
                              hipStream_t stream)
{
    const float* x  = (const float*)d_in[0];
    const float* tx = (const float*)d_in[1];
    const int*   uj = (const int*)d_in[7];
    const float* W1 = (const float*)d_in[8];
    const float* b1 = (const float*)d_in[9];
    const float* W2 = (const float*)d_in[10];
    const float* b2 = (const float*)d_in[11];
    const float* W3 = (const float*)d_in[12];
    const float* b3 = (const float*)d_in[13];

    // d_out = [NCONF energies | NATOMS*3 forces], accumulated via atomics.
    hipMemsetAsync(d_out, 0, (size_t)(NCONF + NATOMS * 3) * sizeof(float), stream);

    fit_main<<<NATOMS, 256, 0, stream>>>(x, tx, uj, W1, b1, W2, b2, W3, b3,
                                         (float*)d_out);
}

// Round 16
// 41.429 us; speedup vs baseline: 1.2808x; 1.2808x over previous
//
#include <hip/hip_runtime.h>
#include <math.h>

#define NATOMS 2000
#define NNBR   30
#define NCONF  8
#define APC    250
#define NRAD   12
#define M3     20
#define H1N    64
#define H2N    32

#define MU(m) (-1.0f + (float)(m) * (2.0f / 19.0f))

typedef __attribute__((ext_vector_type(8))) short short8_t;   // bf16x8 MFMA frag
typedef __attribute__((ext_vector_type(4))) float f32x4;

__device__ __forceinline__ float sigmoidf(float v) {
    return 1.0f / (1.0f + __expf(-v));
}
__device__ __forceinline__ ushort f2bf(float f) {
    unsigned u = __float_as_uint(f);
    u += 0x7FFF + ((u >> 16) & 1);          // RNE
    return (ushort)(u >> 16);
}
__device__ __forceinline__ float bf2f(ushort s) {
    return __uint_as_float(((unsigned)s) << 16);
}

// One atom per 256-thread block.
// MLP fwd+bwd = 4 per-block bf16 MFMA GEMMs (16x16x32).
// Geometry in SoA bank-planes. 3-body bwd: two-pass split-T (Ap-side sums,
// then T[p][q]+T[q][p] combine), T packed as bf16x2 in one u32 plane.
// LDS ~30.4 KB -> 5 blocks/CU.  (R14 configuration — best measured.)
extern "C" __global__ void __launch_bounds__(256)
fit_main(const float* __restrict__ x, const float* __restrict__ tx,
         const int* __restrict__ uj,
         const float* __restrict__ W1, const float* __restrict__ b1,
         const float* __restrict__ W2, const float* __restrict__ b2,
         const float* __restrict__ W3, const float* __restrict__ b3,
         float* __restrict__ gx, float* __restrict__ e_atom)
{
    const int tid  = threadIdx.x;
    const int lane = tid & 63;
    const int wid  = tid >> 6;
    const int atom = blockIdx.x;
    const int lr   = lane & 15;     // MFMA row/col index
    const int lg   = lane >> 4;     // MFMA k-group / reg-group

    // SoA geometry planes: index p hits bank p%32 -> conflict-free q reads
    __shared__ float s_ux[32], s_uy[32], s_uz[32], s_fcp[32];
    __shared__ float s_r[32], s_rinv[32], s_sa[32], s_ca[32];
    __shared__ int   s_j[NNBR];
    __shared__ __align__(16) ushort s_descb[32 * 40];  // bf16 desc [p][d]
    __shared__ __align__(16) ushort s_W1b [32 * 72];   // bf16 W1  [d][h]
    __shared__ __align__(16) ushort s_W2tb[32 * 72];   // bf16 W2t [k][h]
    __shared__ __align__(16) ushort s_h1b [32 * 72];   // h1, later g_z1
    __shared__ __align__(16) ushort s_gz2b[32 * 40];   // gz2
    __shared__ __align__(16) float  s_gd  [32 * 44];   // fp32 gd [p][d]
    __shared__ float    s_outp[64];                    // z3 partials
    __shared__ float    s_red[32 * 5];                 // gu0..2, gfc
    __shared__ unsigned s_Tpk[NNBR * 31];              // bf16(T1)<<16 | bf16(T2)

    const float k1  = 0.6283185307179586f;   // pi/5
    const float sq  = 0.6324555320336759f;   // sqrt(2/5)
    const float eta = 45.125f;               // 1/(2*dmu^2)
    const float RHO = 0.36787944117144233f;  // exp(-1)
    const float C2  = -90.25f;               // -2*eta

    // ---------------- A: stage bf16 weights + pair geometry ----------------
#pragma unroll
    for (int i = 0; i < 8; i++) {
        int idx = tid + 256 * i;               // W1 [32][64]
        s_W1b[(idx >> 6) * 72 + (idx & 63)] = f2bf(W1[idx]);
    }
#pragma unroll
    for (int i = 0; i < 8; i++) {
        int idx = tid + 256 * i;               // W2 [64][32] -> [k][h]
        s_W2tb[(idx & 31) * 72 + (idx >> 5)] = f2bf(W2[idx]);
    }
    if (tid < NNBR) {
        int p = atom * NNBR + tid;
        int j = uj[p];
        float d0 = x[atom * 3 + 0] - x[j * 3 + 0] - tx[p * 3 + 0];
        float d1 = x[atom * 3 + 1] - x[j * 3 + 1] - tx[p * 3 + 1];
        float d2 = x[atom * 3 + 2] - x[j * 3 + 2] - tx[p * 3 + 2];
        float r = sqrtf(d0 * d0 + d1 * d1 + d2 * d2);
        float rinv = 1.0f / r;
        float sa, ca;
        __sincosf(k1 * r, &sa, &ca);
        float fc = 0.5f * (ca + 1.0f);
        s_ux[tid] = d0 * rinv; s_uy[tid] = d1 * rinv; s_uz[tid] = d2 * rinv;
        s_fcp[tid] = fc; s_r[tid] = r; s_rinv[tid] = rinv;
        s_sa[tid] = sa; s_ca[tid] = ca;
        s_j[tid] = j;
    } else if (tid < 32) {
        s_ux[tid] = 0.f; s_uy[tid] = 0.f; s_uz[tid] = 0.f; s_fcp[tid] = 0.f;
        s_r[tid] = 1.f; s_rinv[tid] = 1.f; s_sa[tid] = 0.f; s_ca[tid] = 1.f;
    }
    __syncthreads();

    // ------- B+C: rbf (bf16), pad rows, 3-body forward -> s_descb -------
#pragma unroll 1
    for (int t = tid; t < NNBR * NRAD; t += 256) {
        int p = t / NRAD, n = t - p * NRAD;
        float s = __sinf((float)(n + 1) * k1 * s_r[p]);
        s_descb[p * 40 + n] = f2bf(s_fcp[p] * sq * s * s_rinv[p]);
    }
    if (tid < 80) s_descb[30 * 40 + tid] = 0;      // zero pad rows 30,31
    if (tid < 240) {
        int p = tid >> 3, c = tid & 7;
        int q0 = (c < 6) ? 4 * c : 24 + 3 * (c - 6);
        int qn = (c < 6) ? 4 : 3;
        float up0 = s_ux[p], up1 = s_uy[p], up2 = s_uz[p];
        float d3part[M3];
#pragma unroll
        for (int m = 0; m < M3; m++) d3part[m] = 0.f;
        for (int qq = 0; qq < qn; qq++) {
            int q = q0 + qq;
            float fq = (q == p) ? 0.f : s_fcp[q];
            float cs = up0 * s_ux[q] + up1 * s_uy[q] + up2 * s_uz[q];
            float E  = __expf(9.5f * cs);
            float Ei = __expf(-9.5f * cs);
            float t9 = cs - MU(9);
            float h9 = __expf(-eta * t9 * t9);
            float h = h9 * E, rr = E * RHO;
            d3part[10] = fmaf(fq, h, d3part[10]);
#pragma unroll
            for (int m = 11; m < 20; m++) {
                h *= rr; rr *= RHO;
                d3part[m] = fmaf(fq, h, d3part[m]);
            }
            h = h9; rr = RHO * Ei;
            d3part[9] = fmaf(fq, h, d3part[9]);
#pragma unroll
            for (int m = 8; m >= 0; m--) {
                h *= rr; rr *= RHO;
                d3part[m] = fmaf(fq, h, d3part[m]);
            }
        }
#pragma unroll
        for (int m = 0; m < M3; m++) {
            float v = d3part[m];
            v += __shfl_xor(v, 1);
            v += __shfl_xor(v, 2);
            v += __shfl_xor(v, 4);
            if (c == 0) s_descb[p * 40 + NRAD + m] = f2bf(v);
        }
    }
    __syncthreads();

    // ---- GEMM1: z1 = desc @ W1; h1 = sigmoid(z1+b1) -> s_h1b ----
    {
        const int mt = wid & 1, ntb = (wid >> 1) * 2;
        short8_t a = *(const short8_t*)&s_descb[(16 * mt + lr) * 40 + lg * 8];
#pragma unroll
        for (int t = 0; t < 2; t++) {
            int col = 16 * (ntb + t) + lr;
            short8_t b;
#pragma unroll
            for (int j = 0; j < 8; j++)
                b[j] = (short)s_W1b[(lg * 8 + j) * 72 + col];
            f32x4 c = {0.f, 0.f, 0.f, 0.f};
            c = __builtin_amdgcn_mfma_f32_16x16x32_bf16(a, b, c, 0, 0, 0);
            float b1v = b1[col];
#pragma unroll
            for (int rg = 0; rg < 4; rg++) {
                int p = 16 * mt + lg * 4 + rg;
                s_h1b[p * 72 + col] = f2bf(sigmoidf(c[rg] + b1v));
            }
        }
    }
    __syncthreads();

    // ---- GEMM2: z2 = h1 @ W2; gz2 -> s_gz2b; z3 partials ----
    {
        const int mt = wid & 1, nt = wid >> 1;
        f32x4 c = {0.f, 0.f, 0.f, 0.f};
#pragma unroll
        for (int kt = 0; kt < 2; kt++) {
            short8_t a = *(const short8_t*)&s_h1b[(16 * mt + lr) * 72 + kt * 32 + lg * 8];
            short8_t b = *(const short8_t*)&s_W2tb[(16 * nt + lr) * 72 + kt * 32 + lg * 8];
            c = __builtin_amdgcn_mfma_f32_16x16x32_bf16(a, b, c, 0, 0, 0);
        }
        int k2 = 16 * nt + lr;
        float b2v = b2[k2], w3v = W3[k2];
        float op[4];
#pragma unroll
        for (int rg = 0; rg < 4; rg++) {
            int p = 16 * mt + lg * 4 + rg;
            float s = sigmoidf(c[rg] + b2v);
            op[rg] = s * w3v;
            float g = s_fcp[p] * w3v * s * (1.f - s);   // rows>=30: fc plane = 0
            s_gz2b[p * 40 + k2] = f2bf(g);
        }
#pragma unroll
        for (int rg = 0; rg < 4; rg++) {
            op[rg] += __shfl_xor(op[rg], 1);
            op[rg] += __shfl_xor(op[rg], 2);
            op[rg] += __shfl_xor(op[rg], 4);
            op[rg] += __shfl_xor(op[rg], 8);
        }
        if (lr == 0) {
#pragma unroll
            for (int rg = 0; rg < 4; rg++)
                s_outp[nt * 32 + 16 * mt + lg * 4 + rg] = op[rg];
        }
    }
    __syncthreads();

    // ---- GEMM3: gh1 = gz2 @ W2^T; gz1 = gh1*h1*(1-h1) in place ----
    {
        const int mt = wid & 1, ntb = (wid >> 1) * 2;
        short8_t a = *(const short8_t*)&s_gz2b[(16 * mt + lr) * 40 + lg * 8];
#pragma unroll
        for (int t = 0; t < 2; t++) {
            int hcol = 16 * (ntb + t) + lr;
            short8_t b;
#pragma unroll
            for (int j = 0; j < 8; j++)
                b[j] = (short)s_W2tb[(lg * 8 + j) * 72 + hcol];
            f32x4 c = {0.f, 0.f, 0.f, 0.f};
            c = __builtin_amdgcn_mfma_f32_16x16x32_bf16(a, b, c, 0, 0, 0);
#pragma unroll
            for (int rg = 0; rg < 4; rg++) {
                int p = 16 * mt + lg * 4 + rg;
                float hv = bf2f(s_h1b[p * 72 + hcol]);
                s_h1b[p * 72 + hcol] = f2bf(c[rg] * hv * (1.f - hv));
            }
        }
    }
    __syncthreads();

    // ---- GEMM4: gd = gz1 @ W1^T -> s_gd fp32 ----
    {
        const int mt = wid & 1, nt = wid >> 1;
        f32x4 c = {0.f, 0.f, 0.f, 0.f};
#pragma unroll
        for (int kt = 0; kt < 2; kt++) {
            short8_t a = *(const short8_t*)&s_h1b[(16 * mt + lr) * 72 + kt * 32 + lg * 8];
            short8_t b = *(const short8_t*)&s_W1b[(16 * nt + lr) * 72 + kt * 32 + lg * 8];
            c = __builtin_amdgcn_mfma_f32_16x16x32_bf16(a, b, c, 0, 0, 0);
        }
        int d = 16 * nt + lr;
#pragma unroll
        for (int rg = 0; rg < 4; rg++)
            s_gd[(16 * mt + lg * 4 + rg) * 44 + d] = c[rg];
    }
    __syncthreads();

    // ---- I-a: Ap-side sums per ordered (p,q) -> packed T (no Aq loads) ----
    if (tid < 240) {
        int p = tid >> 3, c = tid & 7;
        int q0 = (c < 6) ? 4 * c : 24 + 3 * (c - 6);
        int qn = (c < 6) ? 4 : 3;
        float up0 = s_ux[p], up1 = s_uy[p], up2 = s_uz[p];
        float Ap[M3];
        {
            const f32x4* ap4 = (const f32x4*)(s_gd + p * 44 + NRAD);
#pragma unroll
            for (int t4 = 0; t4 < 5; t4++) {
                f32x4 v = ap4[t4];
                Ap[4 * t4 + 0] = v[0]; Ap[4 * t4 + 1] = v[1];
                Ap[4 * t4 + 2] = v[2]; Ap[4 * t4 + 3] = v[3];
            }
        }
        for (int qq = 0; qq < qn; qq++) {
            int q = q0 + qq;
            float cs = up0 * s_ux[q] + up1 * s_uy[q] + up2 * s_uz[q];
            float E  = __expf(9.5f * cs);
            float Ei = __expf(-9.5f * cs);
            float t9 = cs - MU(9);
            float h9 = __expf(-eta * t9 * t9);
            float SAh = 0.f, SAm = 0.f;
            {
                float h = h9 * E, rr = E * RHO;
#pragma unroll
                for (int m = 10; m < 20; m++) {
                    if (m > 10) { h *= rr; rr *= RHO; }
                    SAh = fmaf(Ap[m], h, SAh);
                    SAm = fmaf(Ap[m], MU(m) * h, SAm);
                }
            }
            {
                float h = h9, rr = RHO * Ei;
#pragma unroll
                for (int m = 9; m >= 0; m--) {
                    if (m < 9) { h *= rr; rr *= RHO; }
                    SAh = fmaf(Ap[m], h, SAh);
                    SAm = fmaf(Ap[m], MU(m) * h, SAm);
                }
            }
            float t1 = cs * SAh - SAm, t2 = SAh;
            unsigned pk = (q == p) ? 0u
                        : (((unsigned)f2bf(t1) << 16) | (unsigned)f2bf(t2));
            s_Tpk[p * 31 + q] = pk;
        }
    }
    __syncthreads();

    // ---- I-b: combine T[p][q] with T[q][p]; shfl-reduced over chunks ----
    if (tid < 240) {
        int p = tid >> 3, c = tid & 7;
        int q0 = (c < 6) ? 4 * c : 24 + 3 * (c - 6);
        int qn = (c < 6) ? 4 : 3;
        float fp_ = s_fcp[p];
        float gu0 = 0.f, gu1 = 0.f, gu2 = 0.f, gfc = 0.f;
        for (int qq = 0; qq < qn; qq++) {
            int q = q0 + qq;
            float fq = s_fcp[q];
            unsigned pkA = s_Tpk[p * 31 + q];
            unsigned pkB = s_Tpk[q * 31 + p];
            float gcos = C2 * (fq * bf2f((ushort)(pkA >> 16))
                             + fp_ * bf2f((ushort)(pkB >> 16)));
            gu0 = fmaf(gcos, s_ux[q], gu0);
            gu1 = fmaf(gcos, s_uy[q], gu1);
            gu2 = fmaf(gcos, s_uz[q], gu2);
            gfc += bf2f((ushort)(pkB & 0xffff));
        }
        gu0 += __shfl_xor(gu0, 1); gu0 += __shfl_xor(gu0, 2); gu0 += __shfl_xor(gu0, 4);
        gu1 += __shfl_xor(gu1, 1); gu1 += __shfl_xor(gu1, 2); gu1 += __shfl_xor(gu1, 4);
        gu2 += __shfl_xor(gu2, 1); gu2 += __shfl_xor(gu2, 2); gu2 += __shfl_xor(gu2, 4);
        gfc += __shfl_xor(gfc, 1); gfc += __shfl_xor(gfc, 2); gfc += __shfl_xor(gfc, 4);
        if (c == 0) {
            s_red[p * 5 + 0] = gu0;
            s_red[p * 5 + 1] = gu1;
            s_red[p * 5 + 2] = gu2;
            s_red[p * 5 + 3] = gfc;
        }
    }
    __syncthreads();

    // ---------------- K: rbf backward + final per-pair + scatter ------------
    float gd0 = 0.f, gd1 = 0.f, gd2 = 0.f, eij = 0.f;
    if (tid < NNBR) {
        float fc = s_fcp[tid], rinv = s_rinv[tid];
        float sa = s_sa[tid], ca = s_ca[tid];
        float out = b3[0] + s_outp[tid] + s_outp[32 + tid];
        float u0 = s_ux[tid], u1 = s_uy[tid], u2 = s_uz[tid];
        int j = s_j[tid];
        float grp = 0.f, gfp = 0.f;
        float sprev = 0.f, scur = sa, cprev = 1.f, ccur = ca;
#pragma unroll
        for (int d = 0; d < NRAD; d++) {
            float gdv = s_gd[tid * 44 + d];
            float n = (float)(d + 1);
            grp += gdv * fc * sq * rinv * (n * k1 * ccur - scur * rinv);
            gfp += gdv * sq * scur * rinv;
            float snext = 2.f * ca * scur - sprev; sprev = scur; scur = snext;
            float cnext = 2.f * ca * ccur - cprev; cprev = ccur; ccur = cnext;
        }
        float gfc = gfp + s_red[tid * 5 + 3] + out;
        float gu0 = s_red[tid * 5 + 0];
        float gu1 = s_red[tid * 5 + 1];
        float gu2 = s_red[tid * 5 + 2];
        float grf = grp + gfc * (-0.5f * k1 * sa);
        float gdot = gu0 * u0 + gu1 * u1 + gu2 * u2;
        gd0 = grf * u0 + (gu0 - gdot * u0) * rinv;
        gd1 = grf * u1 + (gu1 - gdot * u1) * rinv;
        gd2 = grf * u2 + (gu2 - gdot * u2) * rinv;
        atomicAdd(&gx[j * 3 + 0], -gd0);
        atomicAdd(&gx[j * 3 + 1], -gd1);
        atomicAdd(&gx[j * 3 + 2], -gd2);
        eij = out * fc;
    }
    if (wid == 0) {
#pragma unroll
        for (int off = 32; off > 0; off >>= 1) {
            gd0 += __shfl_xor(gd0, off);
            gd1 += __shfl_xor(gd1, off);
            gd2 += __shfl_xor(gd2, off);
            eij += __shfl_xor(eij, off);
        }
        if (tid == 0) {
            atomicAdd(&gx[atom * 3 + 0], gd0);
            atomicAdd(&gx[atom * 3 + 1], gd1);
            atomicAdd(&gx[atom * 3 + 2], gd2);
            e_atom[atom] = eij;
        }
    }
}

// blocks 0..7: per-config energy reduction; blocks 8..: forces = -gx
extern "C" __global__ void __launch_bounds__(256)
fit_finalize(const float* __restrict__ e_atom, const float* __restrict__ gx,
             float* __restrict__ out)
{
    int b = blockIdx.x;
    if (b < NCONF) {
        __shared__ float red[256];
        int t = threadIdx.x;
        red[t] = (t < APC) ? e_atom[b * APC + t] : 0.f;
        __syncthreads();
        for (int s = 128; s > 0; s >>= 1) {
            if (t < s) red[t] += red[t + s];
            __syncthreads();
        }
        if (t == 0) out[b] = red[0];
    } else {
        int idx = (b - NCONF) * 256 + threadIdx.x;
        if (idx < NATOMS * 3) out[NCONF + idx] = -gx[idx];
    }
}

extern "C" void kernel_launch(void* const* d_in, const int* in_sizes, int n_in,
                              void* d_out, int out_size, void* d_ws, size_t ws_size,
                              hipStream_t stream)
{
    const float* x  = (const float*)d_in[0];
    const float* tx = (const float*)d_in[1];
    const int*   uj = (const int*)d_in[7];
    const float* W1 = (const float*)d_in[8];
    const float* b1 = (const float*)d_in[9];
    const float* W2 = (const float*)d_in[10];
    const float* b2 = (const float*)d_in[11];
    const float* W3 = (const float*)d_in[12];
    const float* b3 = (const float*)d_in[13];

    float* gx     = (float*)d_ws;           // [NATOMS*3]
    float* e_atom = gx + NATOMS * 3;        // [NATOMS]

    hipMemsetAsync(gx, 0, NATOMS * 3 * sizeof(float), stream);

    fit_main<<<NATOMS, 256, 0, stream>>>(x, tx, uj, W1, b1, W2, b2, W3, b3,
                                         gx, e_atom);

    int fblocks = NCONF + (NATOMS * 3 + 255) / 256;   // 8 + 24
    fit_finalize<<<fblocks, 256, 0, stream>>>(e_atom, gx, (float*)d_out);
}